// Round 1
// baseline (245.252 us; speedup 1.0000x reference)
//
#include <hip/hip_runtime.h>

#define BB 8
#define NN 2048
#define DD 1024
#define GG 8
#define CAP 320
#define NTOK (BB * NN)
#define EPSV 1e-9f
#define THRESH 0.2f

// ---------------------------------------------------------------------------
// Kernel 1: logits GEMV + softmax + top2 + normalize + threshold.
// One wave handles 4 tokens. W staged transposed in LDS: Wt[e][k], read as
// float4 with consecutive-lane addresses (conflict-free b128 pattern).
// Record per token: {int e1, float g1n, int e2_or_-1, float g2n}.
// ---------------------------------------------------------------------------
__global__ __launch_bounds__(256) void gate_kernel(const float* __restrict__ x,
                                                   const float* __restrict__ W,
                                                   float4* __restrict__ rec) {
    __shared__ float Wt[GG * DD];
    const float4* W4 = (const float4*)W;
    for (int r = threadIdx.x; r < DD; r += 256) {
        float4 a = W4[r * 2];
        float4 b = W4[r * 2 + 1];
        Wt[0 * DD + r] = a.x; Wt[1 * DD + r] = a.y;
        Wt[2 * DD + r] = a.z; Wt[3 * DD + r] = a.w;
        Wt[4 * DD + r] = b.x; Wt[5 * DD + r] = b.y;
        Wt[6 * DD + r] = b.z; Wt[7 * DD + r] = b.w;
    }
    __syncthreads();

    const int wave = threadIdx.x >> 6;
    const int lane = threadIdx.x & 63;
    const int t0 = blockIdx.x * 16 + wave * 4;   // 1024 blocks * 16 tokens

    const float4* xr0 = (const float4*)(x + (size_t)(t0 + 0) * DD);
    const float4* xr1 = (const float4*)(x + (size_t)(t0 + 1) * DD);
    const float4* xr2 = (const float4*)(x + (size_t)(t0 + 2) * DD);
    const float4* xr3 = (const float4*)(x + (size_t)(t0 + 3) * DD);
    const float4* Wt4 = (const float4*)Wt;

    float acc[4][8];
#pragma unroll
    for (int t = 0; t < 4; t++)
#pragma unroll
        for (int e = 0; e < 8; e++) acc[t][e] = 0.f;

#pragma unroll
    for (int j = 0; j < 4; j++) {
        const int idx = j * 64 + lane;           // float4 index in row, 0..255
        float4 wv[8];
#pragma unroll
        for (int e = 0; e < 8; e++) wv[e] = Wt4[e * (DD / 4) + idx];
        float4 xv0 = xr0[idx];
        float4 xv1 = xr1[idx];
        float4 xv2 = xr2[idx];
        float4 xv3 = xr3[idx];
#pragma unroll
        for (int e = 0; e < 8; e++) {
            acc[0][e] += xv0.x * wv[e].x + xv0.y * wv[e].y + xv0.z * wv[e].z + xv0.w * wv[e].w;
            acc[1][e] += xv1.x * wv[e].x + xv1.y * wv[e].y + xv1.z * wv[e].z + xv1.w * wv[e].w;
            acc[2][e] += xv2.x * wv[e].x + xv2.y * wv[e].y + xv2.z * wv[e].z + xv2.w * wv[e].w;
            acc[3][e] += xv3.x * wv[e].x + xv3.y * wv[e].y + xv3.z * wv[e].z + xv3.w * wv[e].w;
        }
    }

    // butterfly reduce across the 64 lanes: afterwards every lane has totals
#pragma unroll
    for (int off = 32; off > 0; off >>= 1) {
#pragma unroll
        for (int t = 0; t < 4; t++)
#pragma unroll
            for (int e = 0; e < 8; e++)
                acc[t][e] += __shfl_xor(acc[t][e], off, 64);
    }

    if (lane == 0) {
#pragma unroll
        for (int t = 0; t < 4; t++) {
            float mx = acc[t][0];
#pragma unroll
            for (int e = 1; e < 8; e++) mx = fmaxf(mx, acc[t][e]);
            float p[8];
            float s = 0.f;
#pragma unroll
            for (int e = 0; e < 8; e++) { p[e] = __expf(acc[t][e] - mx); s += p[e]; }
            const float inv = 1.f / s;
            // top-1 (first occurrence on ties, like argmax)
            int e1 = 0; float g1 = p[0];
#pragma unroll
            for (int e = 1; e < 8; e++) if (p[e] > g1) { g1 = p[e]; e1 = e; }
            // top-2: argmax over gates with top-1 zeroed
            int e2 = -1; float g2 = -1.f;
#pragma unroll
            for (int e = 0; e < 8; e++) if (e != e1 && p[e] > g2) { g2 = p[e]; e2 = e; }
            g1 *= inv; g2 *= inv;
            // faithful to reference: gate_1 updated first, gate_2 uses updated gate_1
            const float g1n = g1 / (g1 + g2 + EPSV);
            const float g2n = g2 / (g1n + g2 + EPSV);
            if (!(g2n > THRESH)) e2 = -1;   // threshold folds into invalid expert
            rec[t0 + t] = make_float4(__int_as_float(e1), g1n, __int_as_float(e2), g2n);
        }
    }
}

// ---------------------------------------------------------------------------
// Kernel 2: per-batch sequential scan over tokens (exclusive cumsum per gate)
// via ballot/popcount, 64 tokens per step. One wave per batch; all 32 chunk
// records held in registers (occupancy irrelevant: 8 waves total).
// Output record: {int o1_or_-1, float g1, int o2_or_-1, float g2} where
// o = expert*CAP + position (slab-flat offset).
// ---------------------------------------------------------------------------
__global__ __launch_bounds__(64) void scan_kernel(const float4* __restrict__ rin,
                                                  float4* __restrict__ rout) {
    const int b = blockIdx.x;
    const int lane = threadIdx.x;
    const int base = b * NN;
    const unsigned long long lt = (1ull << lane) - 1ull;   // lanes below me

    float4 recs[32];
#pragma unroll
    for (int i = 0; i < 32; i++) recs[i] = rin[base + i * 64 + lane];

    int pos1[32];
    int cnt[8] = {0, 0, 0, 0, 0, 0, 0, 0};

    // pass 1: positions in expert for top-1 choices (mask_1 is always 1 pre-capacity)
#pragma unroll
    for (int i = 0; i < 32; i++) {
        const int e1 = __float_as_int(recs[i].x);
        int p = 0;
#pragma unroll
        for (int g = 0; g < 8; g++) {
            const bool is = (e1 == g);
            const unsigned long long m = __ballot(is);
            if (is) p = cnt[g] + __popcll(m & lt);
            cnt[g] += __popcll(m);
        }
        pos1[i] = p;
    }

    // mask_1_count (post-capacity) = min(count, CAP) -> base offset for expert-2
#pragma unroll
    for (int g = 0; g < 8; g++) cnt[g] = min(cnt[g], CAP);

    // pass 2: positions for thresholded top-2 choices, offset by mask_1_count
#pragma unroll
    for (int i = 0; i < 32; i++) {
        const int e2 = __float_as_int(recs[i].z);
        int p2 = CAP;   // sentinel: invalid unless set below
#pragma unroll
        for (int g = 0; g < 8; g++) {
            const bool is = (e2 == g);
            const unsigned long long m = __ballot(is);
            if (is) p2 = cnt[g] + __popcll(m & lt);
            cnt[g] += __popcll(m);
        }
        const int e1 = __float_as_int(recs[i].x);
        const int o1 = (pos1[i] < CAP) ? (e1 * CAP + pos1[i]) : -1;
        const int o2 = (e2 >= 0 && p2 < CAP) ? (e2 * CAP + p2) : -1;
        rout[base + i * 64 + lane] =
            make_float4(__int_as_float(o1), recs[i].y, __int_as_float(o2), recs[i].w);
    }
}

// ---------------------------------------------------------------------------
// Kernel 3: write the output. One wave per token slab (8*320 = 2560 floats =
// 10 KiB). Each lane stores 10 float4s, folding the <=2 scatter values into
// the right components branchlessly. Single pass, fully coalesced.
// ---------------------------------------------------------------------------
__global__ __launch_bounds__(256) void write_kernel(const float4* __restrict__ rec,
                                                    float* __restrict__ out) {
    const int wave = threadIdx.x >> 6;
    const int lane = threadIdx.x & 63;
    const int token = blockIdx.x * 4 + wave;

    const float4 r = rec[token];   // broadcast load (same addr across wave)
    const int o1 = __float_as_int(r.x);
    const float g1 = r.y;
    const int o2 = __float_as_int(r.z);
    const float g2 = r.w;

    float4* out4 = (float4*)(out + (size_t)token * (GG * CAP));
#pragma unroll
    for (int i = 0; i < 10; i++) {
        const int q = lane + i * 64;   // float4 index, 0..639
        const int f = q * 4;           // flat float index in slab
        float4 v;
        v.x = (f + 0 == o1) ? g1 : ((f + 0 == o2) ? g2 : 0.f);
        v.y = (f + 1 == o1) ? g1 : ((f + 1 == o2) ? g2 : 0.f);
        v.z = (f + 2 == o1) ? g1 : ((f + 2 == o2) ? g2 : 0.f);
        v.w = (f + 3 == o1) ? g1 : ((f + 3 == o2) ? g2 : 0.f);
        out4[q] = v;
    }
}

extern "C" void kernel_launch(void* const* d_in, const int* in_sizes, int n_in,
                              void* d_out, int out_size, void* d_ws, size_t ws_size,
                              hipStream_t stream) {
    const float* x = (const float*)d_in[0];          // [8, 2048, 1024] fp32
    const float* W = (const float*)d_in[1];          // [1024, 8] fp32
    float* out = (float*)d_out;                      // [8, 2048, 8, 320] fp32

    float4* rec1 = (float4*)d_ws;                    // 16384 * 16 B
    float4* rec2 = rec1 + NTOK;                      // 16384 * 16 B

    gate_kernel<<<NTOK / 16, 256, 0, stream>>>(x, W, rec1);
    scan_kernel<<<BB, 64, 0, stream>>>(rec1, rec2);
    write_kernel<<<NTOK / 4, 256, 0, stream>>>(rec2, out);
}

// Round 2
// 242.461 us; speedup vs baseline: 1.0115x; 1.0115x over previous
//
#include <hip/hip_runtime.h>

#define BB 8
#define NN 2048
#define DD 1024
#define GG 8
#define CAP 320
#define NTOK (BB * NN)
#define EPSV 1e-9f
#define THRESH 0.2f

// ---------------------------------------------------------------------------
// Kernel 1: logits GEMV + softmax + top2 + normalize + threshold.
// One wave handles 4 tokens. W staged transposed in LDS: Wt[e][k], read as
// float4 with consecutive-lane addresses (conflict-free b128 pattern).
// Record per token: {int e1, float g1n, int e2_or_-1, float g2n}.
// ---------------------------------------------------------------------------
__global__ __launch_bounds__(256) void gate_kernel(const float* __restrict__ x,
                                                   const float* __restrict__ W,
                                                   float4* __restrict__ rec) {
    __shared__ float Wt[GG * DD];
    const float4* W4 = (const float4*)W;
    for (int r = threadIdx.x; r < DD; r += 256) {
        float4 a = W4[r * 2];
        float4 b = W4[r * 2 + 1];
        Wt[0 * DD + r] = a.x; Wt[1 * DD + r] = a.y;
        Wt[2 * DD + r] = a.z; Wt[3 * DD + r] = a.w;
        Wt[4 * DD + r] = b.x; Wt[5 * DD + r] = b.y;
        Wt[6 * DD + r] = b.z; Wt[7 * DD + r] = b.w;
    }
    __syncthreads();

    const int wave = threadIdx.x >> 6;
    const int lane = threadIdx.x & 63;
    const int t0 = blockIdx.x * 16 + wave * 4;   // 1024 blocks * 16 tokens

    const float4* xr0 = (const float4*)(x + (size_t)(t0 + 0) * DD);
    const float4* xr1 = (const float4*)(x + (size_t)(t0 + 1) * DD);
    const float4* xr2 = (const float4*)(x + (size_t)(t0 + 2) * DD);
    const float4* xr3 = (const float4*)(x + (size_t)(t0 + 3) * DD);
    const float4* Wt4 = (const float4*)Wt;

    float acc[4][8];
#pragma unroll
    for (int t = 0; t < 4; t++)
#pragma unroll
        for (int e = 0; e < 8; e++) acc[t][e] = 0.f;

#pragma unroll
    for (int j = 0; j < 4; j++) {
        const int idx = j * 64 + lane;           // float4 index in row, 0..255
        float4 wv[8];
#pragma unroll
        for (int e = 0; e < 8; e++) wv[e] = Wt4[e * (DD / 4) + idx];
        float4 xv0 = xr0[idx];
        float4 xv1 = xr1[idx];
        float4 xv2 = xr2[idx];
        float4 xv3 = xr3[idx];
#pragma unroll
        for (int e = 0; e < 8; e++) {
            acc[0][e] += xv0.x * wv[e].x + xv0.y * wv[e].y + xv0.z * wv[e].z + xv0.w * wv[e].w;
            acc[1][e] += xv1.x * wv[e].x + xv1.y * wv[e].y + xv1.z * wv[e].z + xv1.w * wv[e].w;
            acc[2][e] += xv2.x * wv[e].x + xv2.y * wv[e].y + xv2.z * wv[e].z + xv2.w * wv[e].w;
            acc[3][e] += xv3.x * wv[e].x + xv3.y * wv[e].y + xv3.z * wv[e].z + xv3.w * wv[e].w;
        }
    }

    // butterfly reduce across the 64 lanes: afterwards every lane has totals
#pragma unroll
    for (int off = 32; off > 0; off >>= 1) {
#pragma unroll
        for (int t = 0; t < 4; t++)
#pragma unroll
            for (int e = 0; e < 8; e++)
                acc[t][e] += __shfl_xor(acc[t][e], off, 64);
    }

    if (lane == 0) {
#pragma unroll
        for (int t = 0; t < 4; t++) {
            float mx = acc[t][0];
#pragma unroll
            for (int e = 1; e < 8; e++) mx = fmaxf(mx, acc[t][e]);
            float p[8];
            float s = 0.f;
#pragma unroll
            for (int e = 0; e < 8; e++) { p[e] = __expf(acc[t][e] - mx); s += p[e]; }
            const float inv = 1.f / s;
            // top-1 (first occurrence on ties, like argmax)
            int e1 = 0; float g1 = p[0];
#pragma unroll
            for (int e = 1; e < 8; e++) if (p[e] > g1) { g1 = p[e]; e1 = e; }
            // top-2: argmax over gates with top-1 zeroed
            int e2 = -1; float g2 = -1.f;
#pragma unroll
            for (int e = 0; e < 8; e++) if (e != e1 && p[e] > g2) { g2 = p[e]; e2 = e; }
            g1 *= inv; g2 *= inv;
            // faithful to reference: gate_1 updated first, gate_2 uses updated gate_1
            const float g1n = g1 / (g1 + g2 + EPSV);
            const float g2n = g2 / (g1n + g2 + EPSV);
            if (!(g2n > THRESH)) e2 = -1;   // threshold folds into invalid expert
            rec[t0 + t] = make_float4(__int_as_float(e1), g1n, __int_as_float(e2), g2n);
        }
    }
}

// ---------------------------------------------------------------------------
// Kernel 2: per-batch sequential scan over tokens (exclusive cumsum per gate)
// via ballot/popcount, 64 tokens per step. One wave per batch; all 32 chunk
// records held in registers (occupancy irrelevant: 8 waves total).
// Output record: {int o1_or_-1, float g1, int o2_or_-1, float g2} where
// o = expert*CAP + position (slab-flat offset).
// ---------------------------------------------------------------------------
__global__ __launch_bounds__(64) void scan_kernel(const float4* __restrict__ rin,
                                                  float4* __restrict__ rout) {
    const int b = blockIdx.x;
    const int lane = threadIdx.x;
    const int base = b * NN;
    const unsigned long long lt = (1ull << lane) - 1ull;   // lanes below me

    float4 recs[32];
#pragma unroll
    for (int i = 0; i < 32; i++) recs[i] = rin[base + i * 64 + lane];

    int pos1[32];
    int cnt[8] = {0, 0, 0, 0, 0, 0, 0, 0};

    // pass 1: positions in expert for top-1 choices (mask_1 is always 1 pre-capacity)
#pragma unroll
    for (int i = 0; i < 32; i++) {
        const int e1 = __float_as_int(recs[i].x);
        int p = 0;
#pragma unroll
        for (int g = 0; g < 8; g++) {
            const bool is = (e1 == g);
            const unsigned long long m = __ballot(is);
            if (is) p = cnt[g] + __popcll(m & lt);
            cnt[g] += __popcll(m);
        }
        pos1[i] = p;
    }

    // mask_1_count (post-capacity) = min(count, CAP) -> base offset for expert-2
#pragma unroll
    for (int g = 0; g < 8; g++) cnt[g] = min(cnt[g], CAP);

    // pass 2: positions for thresholded top-2 choices, offset by mask_1_count
#pragma unroll
    for (int i = 0; i < 32; i++) {
        const int e2 = __float_as_int(recs[i].z);
        int p2 = CAP;   // sentinel: invalid unless set below
#pragma unroll
        for (int g = 0; g < 8; g++) {
            const bool is = (e2 == g);
            const unsigned long long m = __ballot(is);
            if (is) p2 = cnt[g] + __popcll(m & lt);
            cnt[g] += __popcll(m);
        }
        const int e1 = __float_as_int(recs[i].x);
        const int o1 = (pos1[i] < CAP) ? (e1 * CAP + pos1[i]) : -1;
        const int o2 = (e2 >= 0 && p2 < CAP) ? (e2 * CAP + p2) : -1;
        rout[base + i * 64 + lane] =
            make_float4(__int_as_float(o1), recs[i].y, __int_as_float(o2), recs[i].w);
    }
}

// ---------------------------------------------------------------------------
// Kernel 3: scatter the <=2 nonzeros per token into the memset-zeroed output.
// One thread per token; 16K threads total, ~2 dword stores each. The bulk
// zero-fill is done by hipMemsetAsync (fill path measured at 6.5 TB/s).
// ---------------------------------------------------------------------------
__global__ __launch_bounds__(256) void scatter_kernel(const float4* __restrict__ rec,
                                                      float* __restrict__ out) {
    const int t = blockIdx.x * 256 + threadIdx.x;
    const float4 r = rec[t];
    const int o1 = __float_as_int(r.x);
    const int o2 = __float_as_int(r.z);
    float* slab = out + (size_t)t * (GG * CAP);
    if (o1 >= 0) slab[o1] = r.y;
    if (o2 >= 0) slab[o2] = r.w;
}

extern "C" void kernel_launch(void* const* d_in, const int* in_sizes, int n_in,
                              void* d_out, int out_size, void* d_ws, size_t ws_size,
                              hipStream_t stream) {
    const float* x = (const float*)d_in[0];          // [8, 2048, 1024] fp32
    const float* W = (const float*)d_in[1];          // [1024, 8] fp32
    float* out = (float*)d_out;                      // [8, 2048, 8, 320] fp32

    float4* rec1 = (float4*)d_ws;                    // 16384 * 16 B
    float4* rec2 = rec1 + NTOK;                      // 16384 * 16 B

    // Bulk zero of the output via the fill path (6.5 TB/s measured on this
    // chip). Ordered before the scatter by stream semantics.
    hipMemsetAsync(d_out, 0, (size_t)out_size * sizeof(float), stream);

    gate_kernel<<<NTOK / 16, 256, 0, stream>>>(x, W, rec1);
    scan_kernel<<<BB, 64, 0, stream>>>(rec1, rec2);
    scatter_kernel<<<NTOK / 256, 256, 0, stream>>>(rec2, out);
}